// Round 15
// baseline (73.276 us; speedup 1.0000x reference)
//
#include <hip/hip_runtime.h>

// YOLO decode, MI355X. R14: ANCHOR-SPLIT to widen DRAM read runs.
// Main kernel: block = (b, a, 152-position tile)  [5776 = 38*152 exact].
//   Only 80 class planes + obj needed -> 320B/position LDS -> TS=152:
//   read runs 608B/plane (vs 256B at R13's TS=64), LDS 51.7KB -> 3 blocks/CU
//   (6 waves/SIMD). Conf stores: per-row 320B = 5 FULL lines (320%64==0) at
//   960B stride -> no RMW. Scores -> d_ws contiguous per-anchor layout.
// Box kernel: reads 4 head planes + ws-scores, relayouts via LDS, emits
//   fully contiguous boxes (float4 p-linear) + scores.
// Fallback (ws too small): main writes scores scattered, box skips relayout.

#define NCLS 80
#define NA   3
#define BB   32
#define WW   76
#define HH   76
#define WH   (WW*HH)          // 5776
#define PP   (WH*NA)          // 17328
#define TS   152              // positions per tile (5776 = 38*152)
#define NT   38
#define CROW 84               // LDS row stride words (80 + 4 pad)

typedef float f32x4 __attribute__((ext_vector_type(4)));

__global__ __launch_bounds__(512, 6) void yolo_conf_kernel(
    const float* __restrict__ in,        // (B,255,W,H)
    float* __restrict__ conf,            // (B,P,80)
    float* __restrict__ scores,          // (B,P)      (fallback path)
    float* __restrict__ scores_ws,       // (B,3,WH)   (ws path)
    int use_ws)
{
    __shared__ float cls[TS * CROW];     // 51072 B
    __shared__ float so_arr[TS];         // 608 B

    const int t    = threadIdx.x;
    const int bid  = blockIdx.x;
    const int tile = bid % NT;
    const int ba   = bid / NT;
    const int a    = ba % NA;
    const int b    = ba / NA;
    const int s0   = tile * TS;

    const float* aplane = in + ((size_t)b * 255 + a * 85) * WH;

    // ---- obj plane -> so_arr (152 coalesced loads) ----
    if (t < TS)
        so_arr[t] = 1.0f / (1.0f + __expf(-aplane[(size_t)4 * WH + s0 + t]));

    // ---- stage 80 class planes transposed: 20 plane-quads x 152 sl ----
    // unit = qq*152 + sl; consecutive t -> consecutive sl (coalesced, 608B
    // run per plane per tile). ds_write_b128 into cls[sl][qq*4..+3].
    #pragma unroll 3
    for (int it = 0; it < 6; ++it) {
        int u = it * 512 + t;
        if (u < 20 * TS) {
            int qq = u / TS;               // 0..19
            int sl = u - qq * TS;          // 0..151
            const float* gp = aplane + (size_t)(5 + qq * 4) * WH + s0 + sl;
            float v0 = gp[0];
            float v1 = gp[(size_t)1 * WH];
            float v2 = gp[(size_t)2 * WH];
            float v3 = gp[(size_t)3 * WH];
            *reinterpret_cast<float4*>(&cls[sl * CROW + qq * 4]) =
                make_float4(v0, v1, v2, v3);
        }
    }

    __syncthreads();

    // ---- conf: 3040 quads q-linear; per row 320B = 5 full lines, NT ----
    // word offset of this block's row sl: (b*PP + (s0+sl)*3 + a)*80
    size_t cbase = ((size_t)b * PP + (size_t)s0 * 3 + a) * NCLS;  // words
    #pragma unroll 3
    for (int it = 0; it < 6; ++it) {
        int q = it * 512 + t;
        if (q < 20 * TS) {
            int sl = q / 20;
            int u  = q - sl * 20;
            float4 tv = *reinterpret_cast<const float4*>(&cls[sl * CROW + u * 4]);
            float so = so_arr[sl];
            f32x4 o;
            o.x = so / (1.0f + __expf(-tv.x));
            o.y = so / (1.0f + __expf(-tv.y));
            o.z = so / (1.0f + __expf(-tv.z));
            o.w = so / (1.0f + __expf(-tv.w));
            __builtin_nontemporal_store(o,
                reinterpret_cast<f32x4*>(conf + cbase + (size_t)sl * 240 + u * 4));
        }
    }

    // ---- scores: thread t<152 reduces its row's 20 quads ----
    if (t < TS) {
        float mx = -1e30f;
        #pragma unroll
        for (int u = 0; u < 20; ++u) {
            float4 v = *reinterpret_cast<const float4*>(&cls[t * CROW + u * 4]);
            mx = fmaxf(mx, fmaxf(fmaxf(v.x, v.y), fmaxf(v.z, v.w)));
        }
        float sc = so_arr[t] * (1.0f / (1.0f + __expf(-mx)));
        if (use_ws) {
            __builtin_nontemporal_store(sc,
                scores_ws + ((size_t)b * NA + a) * WH + s0 + t);
        } else {
            scores[(size_t)b * PP + (size_t)(s0 + t) * 3 + a] = sc;
        }
    }
}

__global__ __launch_bounds__(512, 4) void yolo_box_kernel(
    const float* __restrict__ in,
    const float* __restrict__ anchors,   // [d*3+a]
    float* __restrict__ boxes,           // (B,P,4)
    float* __restrict__ scores,          // (B,P)
    const float* __restrict__ scores_ws, // (B,3,WH)
    int use_ws)
{
    __shared__ float4 box_buf[TS * NA];  // 7296 B
    __shared__ float  sc_buf[TS * NA];   // 1824 B

    const int t    = threadIdx.x;
    const int bid  = blockIdx.x;
    const int tile = bid % NT;
    const int b    = bid / NT;
    const int s0   = tile * TS;

    if (t < TS * NA) {
        int aa = t / TS;                 // anchor (slow) -> coalesced reads
        int sl = t - aa * TS;
        int s  = s0 + sl;
        const float* hp = in + ((size_t)b * 255 + aa * 85) * WH + s;
        float tx = hp[0];
        float ty = hp[(size_t)1 * WH];
        float tw = hp[(size_t)2 * WH];
        float th = hp[(size_t)3 * WH];

        int w = s / HH, h = s - w * HH;
        float sx = 1.0f / (1.0f + __expf(-tx));
        float sy = 1.0f / (1.0f + __expf(-ty));
        float bx = (sx + (float)w) * (1.0f / WW);
        float by = (sy + (float)h) * (1.0f / HH);
        float bw = __expf(tw) * anchors[aa];
        float bh = __expf(th) * anchors[3 + aa];

        box_buf[sl * NA + aa] = make_float4(bx - 0.5f * bw, by - 0.5f * bh,
                                            bx + 0.5f * bw, by + 0.5f * bh);
        if (use_ws)
            sc_buf[sl * NA + aa] = scores_ws[((size_t)b * NA + aa) * WH + s];
    }

    __syncthreads();

    if (t < TS * NA) {                   // p-linear contiguous stores
        float4 bq = box_buf[t];
        f32x4 bo = {bq.x, bq.y, bq.z, bq.w};
        __builtin_nontemporal_store(bo,
            reinterpret_cast<f32x4*>(boxes + ((size_t)b * PP + s0 * 3 + t) * 4));
        if (use_ws) {
            __builtin_nontemporal_store(sc_buf[t],
                scores + (size_t)b * PP + s0 * 3 + t);
        }
    }
}

extern "C" void kernel_launch(void* const* d_in, const int* in_sizes, int n_in,
                              void* d_out, int out_size, void* d_ws, size_t ws_size,
                              hipStream_t stream) {
    const float* in      = (const float*)d_in[0];
    const float* anchors = (const float*)d_in[1];

    float* boxes  = (float*)d_out;                       // B*P*4
    float* conf   = boxes + (size_t)BB * PP * 4;         // B*P*80
    float* scores = conf + (size_t)BB * PP * NCLS;       // B*P

    const size_t ws_need = (size_t)BB * NA * WH * sizeof(float);  // 2,217,984 B
    int use_ws = ws_size >= ws_need ? 1 : 0;
    float* scores_ws = (float*)d_ws;

    yolo_conf_kernel<<<BB * NA * NT, 512, 0, stream>>>(
        in, conf, scores, scores_ws, use_ws);
    yolo_box_kernel<<<BB * NT, 512, 0, stream>>>(
        in, anchors, boxes, scores, scores_ws, use_ws);
}

// Round 16
// 63.836 us; speedup vs baseline: 1.1479x; 1.1479x over previous
//
#include <hip/hip_runtime.h>

// YOLO decode, MI355X. R15 = R13 (69.8us best: TS=64, 512-thread blocks,
// PROW=260 LDS transpose, q-linear wave-contiguous NT conf stores) +
// CHUNKED XCD SWIZZLE: grid 2912 = 8*364 exactly; bid=(hw%8)*364+hw/8 is
// bijective and gives each XCD a contiguous run of 364 logical blocks
// (4 batches x 91 adjacent tiles). Adjacent tiles share misaligned 128B
// boundary lines in all 240 planes; same-XCD L2 now serves them once
// (mechanism behind the measured TS->FETCH law: 184/138/115/102 MB for
// 64/128/256/608B runs across XCD-scattered blocks).

#define NCLS 80
#define NA   3
#define BB   32
#define WW   76
#define HH   76
#define WH   (WW*HH)          // 5776
#define PP   (WH*NA)          // 17328
#define TS   64               // positions per tile
#define NTILE ((WH + TS - 1) / TS)   // 91 (last tile: 16 valid)
#define PROW 260              // LDS row stride (words)
#define NWG  (BB * NTILE)     // 2912 = 8 * 364
#define CPX  (NWG / 8)        // 364 logical blocks per XCD

typedef float f32x4 __attribute__((ext_vector_type(4)));

__global__ __launch_bounds__(512, 4) void yolo_decode_kernel(
    const float* __restrict__ in,       // (B, 255, W, H)
    const float* __restrict__ anchors,  // (2, 3) flat: [d*3 + a]
    float* __restrict__ boxes,          // (B, P, 4)
    float* __restrict__ conf,           // (B, P, 80)
    float* __restrict__ scores)         // (B, P)
{
    __shared__ float  cls[TS * PROW];     // 66560 B
    __shared__ float  so_buf[TS * NA];    // 768 B
    __shared__ float4 box_buf[TS * NA];   // 3072 B

    const int t    = threadIdx.x;
    // chunked XCD swizzle (bijective: 2912 = 8*364)
    const int hw   = blockIdx.x;
    const int bid  = (hw & 7) * CPX + (hw >> 3);
    const int tile = bid % NTILE;
    const int b    = bid / NTILE;
    const int s0   = tile * TS;
    int valid = WH - s0; if (valid > TS) valid = TS;   // 64 or 16

    const float* bplane = in + (size_t)b * 255 * WH;

    // ---- head loads (t<192): wave per anchor, 64 consecutive sl ----
    int a_h   = t >> 6;                 // 0..2 for t<192
    int sl_h  = t & 63;
    int slc_h = sl_h < valid ? sl_h : valid - 1;
    float tx = 0.f, ty = 0.f, tw = 0.f, th = 0.f, to = 0.f;
    if (t < 192) {
        const float* hp = bplane + (size_t)(a_h * 85) * WH + s0 + slc_h;
        tx = hp[0];
        ty = hp[(size_t)1 * WH];
        tw = hp[(size_t)2 * WH];
        th = hp[(size_t)3 * WH];
        to = hp[(size_t)4 * WH];
    }

    // ---- stage 240 class channels transposed into LDS ----
    // unit = (ch-quad 0..59, sl 0..63): 3840 units, <=8/thread.
    // Per wave: qch constant, 64 consecutive sl -> one 256B segment per plane.
    #pragma unroll 4
    for (int it = 0; it < 8; ++it) {
        int u = it * 512 + t;
        if (u < 60 * TS) {
            int qch = u >> 6;              // 0..59
            int sl  = u & 63;
            int slc = sl < valid ? sl : valid - 1;
            int ch0 = qch * 4;             // never straddles an anchor
            int a   = ch0 / 80;
            int c0  = ch0 - a * 80;
            const float* gp = bplane + (size_t)(a * 85 + 5 + c0) * WH + s0 + slc;
            float v0 = gp[0];
            float v1 = gp[(size_t)1 * WH];
            float v2 = gp[(size_t)2 * WH];
            float v3 = gp[(size_t)3 * WH];
            *reinterpret_cast<float4*>(&cls[sl * PROW + ch0]) =
                make_float4(v0, v1, v2, v3);
        }
    }

    // ---- head compute -> LDS bufs (t<192) ----
    if (t < 192) {
        int s = s0 + slc_h;
        int w = s / HH;
        int h = s - w * HH;
        float sx = 1.0f / (1.0f + __expf(-tx));
        float sy = 1.0f / (1.0f + __expf(-ty));
        float bx = (sx + (float)w) * (1.0f / WW);
        float by = (sy + (float)h) * (1.0f / HH);
        float bw = __expf(tw) * anchors[a_h];
        float bh = __expf(th) * anchors[3 + a_h];
        int p = slc_h * 3 + a_h;           // clamped dups write identical data
        box_buf[p] = make_float4(bx - 0.5f * bw, by - 0.5f * bh,
                                 bx + 0.5f * bw, by + 0.5f * bh);
        so_buf[p] = 1.0f / (1.0f + __expf(-to));
    }

    __syncthreads();

    // ---- conf: 3840 quads q-linear => wave-contiguous 16B NT stores ----
    size_t cbase = ((size_t)b * PP + (size_t)s0 * 3) * NCLS;   // word offset
    int vq = valid * 60;
    #pragma unroll 4
    for (int it = 0; it < 8; ++it) {
        int q = it * 512 + t;
        if (q < vq) {
            int p  = q / 20;
            int u  = q - p * 20;
            int sl = p / 3;
            int a  = p - sl * 3;
            float4 tv = *reinterpret_cast<const float4*>(&cls[sl * PROW + a * 80 + u * 4]);
            float so = so_buf[p];
            f32x4 o;
            o.x = so / (1.0f + __expf(-tv.x));
            o.y = so / (1.0f + __expf(-tv.y));
            o.z = so / (1.0f + __expf(-tv.z));
            o.w = so / (1.0f + __expf(-tv.w));
            __builtin_nontemporal_store(o,
                reinterpret_cast<f32x4*>(conf + cbase + (size_t)q * 4));
        }
    }

    // ---- boxes + scores (t<192), wave-contiguous NT stores ----
    if (t < 192) {
        int p = t;
        if (p < valid * 3) {
            float4 bq = box_buf[p];
            f32x4 bo = {bq.x, bq.y, bq.z, bq.w};
            __builtin_nontemporal_store(bo,
                reinterpret_cast<f32x4*>(boxes + ((size_t)b * PP + s0 * 3 + p) * 4));
        }
        int sl = p / 3;
        int a  = p - sl * 3;
        float mx = -1e30f;
        #pragma unroll
        for (int c4 = 0; c4 < 20; ++c4) {
            float4 v = *reinterpret_cast<const float4*>(&cls[sl * PROW + a * 80 + c4 * 4]);
            mx = fmaxf(mx, fmaxf(fmaxf(v.x, v.y), fmaxf(v.z, v.w)));
        }
        float sc = so_buf[p] * (1.0f / (1.0f + __expf(-mx)));
        if (p < valid * 3) {
            __builtin_nontemporal_store(sc, scores + (size_t)b * PP + s0 * 3 + p);
        }
    }
}

extern "C" void kernel_launch(void* const* d_in, const int* in_sizes, int n_in,
                              void* d_out, int out_size, void* d_ws, size_t ws_size,
                              hipStream_t stream) {
    const float* in      = (const float*)d_in[0];
    const float* anchors = (const float*)d_in[1];

    float* boxes  = (float*)d_out;                       // B*P*4
    float* conf   = boxes + (size_t)BB * PP * 4;         // B*P*80
    float* scores = conf + (size_t)BB * PP * NCLS;       // B*P

    yolo_decode_kernel<<<NWG, 512, 0, stream>>>(in, anchors, boxes, conf, scores);
}

// Round 17
// 60.995 us; speedup vs baseline: 1.2013x; 1.0466x over previous
//
#include <hip/hip_runtime.h>

// YOLO decode, MI355X. R16 = R15 (63.8us: XCD swizzle, NT wave-contiguous
// stores, LDS transpose) with ANCHOR-PHASED LDS to double co-residency:
//  - score(s,a) needs only anchor a's 80 channels -> loop a=0..2 over ONE
//    cls[76][84] buffer (25.5KB; block total ~31KB) -> 4 blocks/CU x 8 waves
//    = 32 waves/CU (HW cap; R15 was 2 blocks/CU, OccupancyPercent 40).
//  - TS 64->76 (5776 = 76*76, tail-free; 304B read runs), grid 2432 = 8*304
//    keeps chunked XCD swizzle bijective.
//  - conf stores per anchor-phase: 320B rows = 5 FULL lines, 320B-aligned
//    (R14-proven, no RMW). boxes/scores p-linear contiguous at the end.

#define NCLS 80
#define NA   3
#define BB   32
#define WW   76
#define HH   76
#define WH   (WW*HH)          // 5776
#define PP   (WH*NA)          // 17328
#define TS   76               // positions per tile (5776 = 76*76)
#define NTILE 76
#define CROW 84               // cls row stride (words)
#define NWG  (BB * NTILE)     // 2432 = 8 * 304
#define CPX  (NWG / 8)        // 304

typedef float f32x4 __attribute__((ext_vector_type(4)));

__global__ __launch_bounds__(512, 8) void yolo_decode_kernel(
    const float* __restrict__ in,       // (B, 255, W, H)
    const float* __restrict__ anchors,  // (2, 3) flat: [d*3 + a]
    float* __restrict__ boxes,          // (B, P, 4)
    float* __restrict__ conf,           // (B, P, 80)
    float* __restrict__ scores)         // (B, P)
{
    __shared__ float  cls[TS * CROW];     // 25536 B
    __shared__ float  so_buf[TS * NA];    // 912 B
    __shared__ float  sc_buf[TS * NA];    // 912 B
    __shared__ float4 box_buf[TS * NA];   // 3648 B

    const int t    = threadIdx.x;
    const int hw   = blockIdx.x;
    const int bid  = (hw & 7) * CPX + (hw >> 3);   // chunked XCD swizzle
    const int tile = bid % NTILE;
    const int b    = bid / NTILE;
    const int s0   = tile * TS;

    const float* bplane = in + (size_t)b * 255 * WH;

    // ---- head (t<228): a_h = t/76, sl_h = t%76; 5 coalesced plane reads ----
    if (t < TS * NA) {
        int a_h  = t / TS;
        int sl_h = t - a_h * TS;
        const float* hp = bplane + (size_t)(a_h * 85) * WH + s0 + sl_h;
        float tx = hp[0];
        float ty = hp[(size_t)1 * WH];
        float tw = hp[(size_t)2 * WH];
        float th = hp[(size_t)3 * WH];
        float to = hp[(size_t)4 * WH];

        int s = s0 + sl_h;
        int w = s / HH;
        int h = s - w * HH;
        float sx = 1.0f / (1.0f + __expf(-tx));
        float sy = 1.0f / (1.0f + __expf(-ty));
        float bx = (sx + (float)w) * (1.0f / WW);
        float by = (sy + (float)h) * (1.0f / HH);
        float bw = __expf(tw) * anchors[a_h];
        float bh = __expf(th) * anchors[3 + a_h];

        int p = sl_h * 3 + a_h;
        box_buf[p] = make_float4(bx - 0.5f * bw, by - 0.5f * bh,
                                 bx + 0.5f * bw, by + 0.5f * bh);
        so_buf[p] = 1.0f / (1.0f + __expf(-to));
    }

    // ---- 3 anchor phases over one cls buffer ----
    for (int a = 0; a < NA; ++a) {
        // stage anchor a's 80 channels: 20 plane-quads x 76 sl = 1520 units
        #pragma unroll
        for (int it = 0; it < 3; ++it) {
            int u = it * 512 + t;
            if (u < 20 * TS) {
                int qq = u / TS;               // 0..19
                int sl = u - qq * TS;          // 0..75
                const float* gp = bplane + (size_t)(a * 85 + 5 + qq * 4) * WH + s0 + sl;
                float v0 = gp[0];
                float v1 = gp[(size_t)1 * WH];
                float v2 = gp[(size_t)2 * WH];
                float v3 = gp[(size_t)3 * WH];
                *reinterpret_cast<float4*>(&cls[sl * CROW + qq * 4]) =
                    make_float4(v0, v1, v2, v3);
            }
        }

        __syncthreads();

        // conf: 1520 quads; rows 320B = 5 full aligned lines, NT
        size_t cbase = ((size_t)b * PP + (size_t)s0 * 3 + a) * NCLS;  // words
        #pragma unroll
        for (int it = 0; it < 3; ++it) {
            int q = it * 512 + t;
            if (q < 20 * TS) {
                int sl = q / 20;
                int u  = q - sl * 20;
                float4 tv = *reinterpret_cast<const float4*>(&cls[sl * CROW + u * 4]);
                float so = so_buf[sl * 3 + a];
                f32x4 o;
                o.x = so / (1.0f + __expf(-tv.x));
                o.y = so / (1.0f + __expf(-tv.y));
                o.z = so / (1.0f + __expf(-tv.z));
                o.w = so / (1.0f + __expf(-tv.w));
                __builtin_nontemporal_store(o,
                    reinterpret_cast<f32x4*>(conf + cbase + (size_t)sl * 240 + u * 4));
            }
        }

        // per-row raw max -> sc_buf (t<76)
        if (t < TS) {
            float mx = -1e30f;
            #pragma unroll
            for (int u = 0; u < 20; ++u) {
                float4 v = *reinterpret_cast<const float4*>(&cls[t * CROW + u * 4]);
                mx = fmaxf(mx, fmaxf(fmaxf(v.x, v.y), fmaxf(v.z, v.w)));
            }
            sc_buf[t * 3 + a] = so_buf[t * 3 + a] * (1.0f / (1.0f + __expf(-mx)));
        }

        __syncthreads();   // protect cls for next phase / sc_buf for tail
    }

    // ---- boxes + scores (t<228), p-linear contiguous NT stores ----
    if (t < TS * NA) {
        float4 bq = box_buf[t];
        f32x4 bo = {bq.x, bq.y, bq.z, bq.w};
        __builtin_nontemporal_store(bo,
            reinterpret_cast<f32x4*>(boxes + ((size_t)b * PP + s0 * 3 + t) * 4));
        __builtin_nontemporal_store(sc_buf[t],
            scores + (size_t)b * PP + s0 * 3 + t);
    }
}

extern "C" void kernel_launch(void* const* d_in, const int* in_sizes, int n_in,
                              void* d_out, int out_size, void* d_ws, size_t ws_size,
                              hipStream_t stream) {
    const float* in      = (const float*)d_in[0];
    const float* anchors = (const float*)d_in[1];

    float* boxes  = (float*)d_out;                       // B*P*4
    float* conf   = boxes + (size_t)BB * PP * 4;         // B*P*80
    float* scores = conf + (size_t)BB * PP * NCLS;       // B*P

    yolo_decode_kernel<<<NWG, 512, 0, stream>>>(in, anchors, boxes, conf, scores);
}